// Round 6
// baseline (1020.503 us; speedup 1.0000x reference)
//
#include <hip/hip_runtime.h>

// ConnectorAttention on MI355X (gfx950), fp16-MFMA implementation.
// Round 9: flash rebuilt for 2x K/V-fragment reuse: 128-thread blocks
//   (2 waves), 64 q-rows/wave (mt=4), KVBLK=32. LDS 40KB (K dbuf 16K +
//   V dbuf 16K + P 8K) -> 4 blocks/CU. Per-wave per-tile LDS issue drops
//   36 b128 + 32 b16 -> 20 b128 + 32 b16 while serving 2x MFMA per
//   fragment (was LDS-issue-bound: 620 cyc LDS vs 310 MFMA). QK streams
//   softmax per-nt (sacc 16 regs); VGPR ~250 capped by launch_bounds(128,2).
//   Pipeline semantics = proven R5 pattern (vmcnt(8) counted, 2 barriers).
//   GEMM: reverted R8 vmcnt deepening (regressed); kept addr precompute.
// Round 7: GEMM m201-style 4 phases/K-tile, BK=64, 2-deep dbuf, 128 KiB.
// Round 3-5: static-max softmax, counted-vmcnt pipelines, XOR swizzles.
// Round 2: workspace 178.1 MiB (reused WT buffer, fp16 pre, attnb aliases pre).

#define DIM 3840
#define NHEADS 30
#define HDIM 128
#define SEQ 2048
#define BATCH 2
#define MROWS (BATCH * SEQ)   // 4096

typedef _Float16 h8 __attribute__((ext_vector_type(8)));
typedef _Float16 h4 __attribute__((ext_vector_type(4)));
typedef float f32x4 __attribute__((ext_vector_type(4)));

#define GP(p) ((const __attribute__((address_space(1))) void*)(p))
#define LP(p) ((__attribute__((address_space(3))) void*)(p))

#define SWZ(row) (((row) & 3) ^ (((row) >> 2) & 3))

// ---------------- conversion kernels ----------------

__global__ __launch_bounds__(256) void convert_h_kernel(
    const float* __restrict__ in, _Float16* __restrict__ out, int n) {
  int i = (blockIdx.x * 256 + threadIdx.x) * 4;
  if (i + 3 < n) {
    float4 v = *reinterpret_cast<const float4*>(in + i);
    h4 o = {(_Float16)v.x, (_Float16)v.y, (_Float16)v.z, (_Float16)v.w};
    *reinterpret_cast<h4*>(out + i) = o;
  }
}

// W [rows][cols] fp32 -> Wt [cols][rows] fp16
__global__ __launch_bounds__(256) void transpose_convert_kernel(
    const float* __restrict__ W, _Float16* __restrict__ Wt, int rows, int cols) {
  __shared__ float tile[32][33];
  int c0 = blockIdx.x * 32, r0 = blockIdx.y * 32;
  int tc = threadIdx.x & 31, tr = threadIdx.x >> 5;
#pragma unroll
  for (int i = 0; i < 32; i += 8)
    tile[tr + i][tc] = W[(size_t)(r0 + tr + i) * cols + c0 + tc];
  __syncthreads();
#pragma unroll
  for (int i = 0; i < 32; i += 8)
    Wt[(size_t)(c0 + tr + i) * rows + r0 + tc] = (_Float16)tile[tc][tr + i];
}

// pre fp16 [B,S,H,D] -> vT fp16 [B,H,D,S]
__global__ __launch_bounds__(256) void transpose_v_kernel(
    const _Float16* __restrict__ pre, _Float16* __restrict__ vT) {
  __shared__ _Float16 tile[32][33];
  int s0 = blockIdx.x * 32, d0 = blockIdx.y * 32, bh = blockIdx.z;
  int b = bh / NHEADS, h = bh % NHEADS;
  int tc = threadIdx.x & 31, tr = threadIdx.x >> 5;
#pragma unroll
  for (int i = 0; i < 32; i += 8) {
    int s = s0 + tr + i, d = d0 + tc;
    tile[tr + i][tc] = pre[((size_t)(b * SEQ + s)) * DIM + h * HDIM + d];
  }
  __syncthreads();
#pragma unroll
  for (int i = 0; i < 32; i += 8) {
    int d = d0 + tr + i, s = s0 + tc;
    vT[((size_t)bh * HDIM + d) * SEQ + s] = tile[tc][tr + i];
  }
}

// ---------------- GEMM: C[M,N] = A[M,K] * Bt[N,K]^T + bias ----------------
// 256x256 tile, BK=64, 512 threads (8 waves, 2Mx4N), fp16 MFMA 16x16x32.
// LDS 128KB: 2 dbufs x (A 256x64 + B 256x64). 4 phases per K-tile (R7
// schedule, R7 vmcnt accounting: boundary vmcnt(4) only).

template <typename OutT>
__global__ __launch_bounds__(512, 2) void gemm_bt_kernel(
    const _Float16* __restrict__ A, const _Float16* __restrict__ Bt,
    const float* __restrict__ bias, OutT* __restrict__ C,
    int M, int N, int K) {
  __shared__ __align__(16) _Float16 smem[65536];  // 2 x (A 16384 + B 16384)
  const int t = threadIdx.x;
  const int wave = t >> 6, lane = t & 63, quad = lane >> 4, l16 = lane & 15;

  // XCD-aware swizzle: nwg=240, 240%8==0 -> bijective simple form
  const int nwg = gridDim.x;
  const int cpx = nwg >> 3;
  const int bid = blockIdx.x;
  const int swz = (bid & 7) * cpx + (bid >> 3);
  const int ntx = N >> 8;                     // tiles along N (15)
  const int bm = (swz / ntx) << 8, bn = (swz % ntx) << 8;
  const int wm = (wave >> 2) * 128, wn = (wave & 3) * 64;

  const _Float16* Abase = A + (size_t)bm * K;
  const _Float16* Bbase = Bt + (size_t)bn * K;
  const int NT = K >> 6;                      // K-tiles of 64 (60)

  f32x4 acc[8][4] = {};

  // per-lane invariant ds byte offsets (row&7 == l16&7 for all frag rows)
  int aOff[2], bOff[2];
#pragma unroll
  for (int ks = 0; ks < 2; ++ks) {
    aOff[ks] = (wm + l16) * 128 + (((ks * 4 + quad) ^ (l16 & 7)) * 16);
    bOff[ks] = 32768 + (wn + l16) * 128 + (((ks * 4 + quad) ^ (l16 & 7)) * 16);
  }
  const char* smem_c = (const char*)smem;

  // stage one half (128 rows x 64 halfs = 16KB) of A (isB=0) or B (isB=1)
  auto stage_half = [&](const _Float16* Gb, int d, int isB, int h, int k0) {
    _Float16* Lb = smem + d * 32768 + isB * 16384 + h * 8192;
#pragma unroll
    for (int L = 0; L < 2; ++L) {
      int slot = L * 512 + t;                 // 0..1023
      int row = h * 128 + (slot >> 3);        // tile row 0..255
      int gs = (slot & 7) ^ (row & 7);        // pre-swizzled source granule
      __builtin_amdgcn_global_load_lds(GP(Gb + (size_t)row * K + k0 + gs * 8),
                                       LP(Lb + slot * 8), 16, 0, 0);
    }
  };

  // prologue: B(0), A(0), B(1) -- 12 loads/thread; wait A(0)+B(0) (8 pops).
  stage_half(Bbase, 0, 1, 0, 0);  stage_half(Bbase, 0, 1, 1, 0);
  stage_half(Abase, 0, 0, 0, 0);  stage_half(Abase, 0, 0, 1, 0);
  stage_half(Bbase, 1, 1, 0, 64); stage_half(Bbase, 1, 1, 1, 64);
  asm volatile("s_waitcnt vmcnt(4)\n\ts_barrier" ::: "memory");

  for (int tt = 0; tt < NT; ++tt) {
    const int ab = (tt & 1) * 65536;          // dbuf byte toggle
    const int dnx = (tt + 1) & 1;
    const int k1 = (tt + 1 < NT ? tt + 1 : NT - 1) << 6;  // A(t+1), clamped
    const int k2 = (tt + 2 < NT ? tt + 2 : NT - 1) << 6;  // B(t+2), clamped
    h8 afl[4], afh[4], bf[4];

    // ---- phase 1: read bf[ks0], afl[ks0]; stage A_lo(t+1); Qlo x ks0 ----
    {
      const char* bp = smem_c + (bOff[0] + ab);
      const char* ap = smem_c + (aOff[0] + ab);
#pragma unroll
      for (int ni = 0; ni < 4; ++ni)
        bf[ni] = *reinterpret_cast<const h8*>(bp + ni * 2048);
#pragma unroll
      for (int mi = 0; mi < 4; ++mi)
        afl[mi] = *reinterpret_cast<const h8*>(ap + mi * 2048);
    }
    stage_half(Abase, dnx, 0, 0, k1);
    __builtin_amdgcn_s_barrier();
    asm volatile("s_waitcnt lgkmcnt(0)" ::: "memory");
    __builtin_amdgcn_sched_barrier(0);
    __builtin_amdgcn_s_setprio(1);
#pragma unroll
    for (int mi = 0; mi < 4; ++mi)
#pragma unroll
      for (int ni = 0; ni < 4; ++ni)
        acc[mi][ni] = __builtin_amdgcn_mfma_f32_16x16x32_f16(afl[mi], bf[ni], acc[mi][ni], 0, 0, 0);
    __builtin_amdgcn_s_setprio(0);
    __builtin_amdgcn_s_barrier();

    // ---- phase 2: read afh[ks0]; stage A_hi(t+1); Qhi x ks0 ----
    {
      const char* ap = smem_c + (aOff[0] + ab);
#pragma unroll
      for (int mi = 0; mi < 4; ++mi)
        afh[mi] = *reinterpret_cast<const h8*>(ap + 8192 + mi * 2048);
    }
    stage_half(Abase, dnx, 0, 1, k1);
    __builtin_amdgcn_s_barrier();
    asm volatile("s_waitcnt lgkmcnt(0)" ::: "memory");
    __builtin_amdgcn_sched_barrier(0);
    __builtin_amdgcn_s_setprio(1);
#pragma unroll
    for (int mi = 0; mi < 4; ++mi)
#pragma unroll
      for (int ni = 0; ni < 4; ++ni)
        acc[4 + mi][ni] = __builtin_amdgcn_mfma_f32_16x16x32_f16(afh[mi], bf[ni], acc[4 + mi][ni], 0, 0, 0);
    __builtin_amdgcn_s_setprio(0);
    __builtin_amdgcn_s_barrier();

    // ---- phase 3: read bf[ks1], afl[ks1]; no stage; Qlo x ks1 ----
    {
      const char* bp = smem_c + (bOff[1] + ab);
      const char* ap = smem_c + (aOff[1] + ab);
#pragma unroll
      for (int ni = 0; ni < 4; ++ni)
        bf[ni] = *reinterpret_cast<const h8*>(bp + ni * 2048);
#pragma unroll
      for (int mi = 0; mi < 4; ++mi)
        afl[mi] = *reinterpret_cast<const h8*>(ap + mi * 2048);
    }
    __builtin_amdgcn_s_barrier();
    asm volatile("s_waitcnt lgkmcnt(0)" ::: "memory");
    __builtin_amdgcn_sched_barrier(0);
    __builtin_amdgcn_s_setprio(1);
#pragma unroll
    for (int mi = 0; mi < 4; ++mi)
#pragma unroll
      for (int ni = 0; ni < 4; ++ni)
        acc[mi][ni] = __builtin_amdgcn_mfma_f32_16x16x32_f16(afl[mi], bf[ni], acc[mi][ni], 0, 0, 0);
    __builtin_amdgcn_s_setprio(0);
    __builtin_amdgcn_s_barrier();

    // ---- phase 4: read afh[ks1]; stage B(t+2) into THIS buf (B dead);
    //      Qhi x ks1; fused vmcnt(4)+barrier = K-tile boundary ----
    {
      const char* ap = smem_c + (aOff[1] + ab);
#pragma unroll
      for (int mi = 0; mi < 4; ++mi)
        afh[mi] = *reinterpret_cast<const h8*>(ap + 8192 + mi * 2048);
    }
    stage_half(Bbase, tt & 1, 1, 0, k2);
    stage_half(Bbase, tt & 1, 1, 1, k2);
    __builtin_amdgcn_s_barrier();
    asm volatile("s_waitcnt lgkmcnt(0)" ::: "memory");
    __builtin_amdgcn_sched_barrier(0);
    __builtin_amdgcn_s_setprio(1);
#pragma unroll
    for (int mi = 0; mi < 4; ++mi)
#pragma unroll
      for (int ni = 0; ni < 4; ++ni)
        acc[4 + mi][ni] = __builtin_amdgcn_mfma_f32_16x16x32_f16(afh[mi], bf[ni], acc[4 + mi][ni], 0, 0, 0);
    __builtin_amdgcn_s_setprio(0);
    // boundary: A(t+1) popped (leaves B(t+2)'s 4 in flight)
    asm volatile("s_waitcnt vmcnt(4)\n\ts_barrier" ::: "memory");
  }

  // drain the tail stages before LDS goes away with the wave
  asm volatile("s_waitcnt vmcnt(0)" ::: "memory");

#pragma unroll
  for (int ni = 0; ni < 4; ++ni) {
    int col = bn + wn + ni * 16 + l16;
    float bv = bias[col];
#pragma unroll
    for (int mi = 0; mi < 8; ++mi) {
      int row0 = bm + wm + mi * 16 + quad * 4;
#pragma unroll
      for (int r = 0; r < 4; ++r)
        C[(size_t)(row0 + r) * N + col] = (OutT)(acc[mi][ni][r] + bv);
    }
  }
}

// ---------------- RMSNorm (row of 3840, fp16 in) -> fp16 [B,H,S,D] --------

__global__ __launch_bounds__(256) void rmsnorm_qk_kernel(
    const _Float16* __restrict__ pre, const float* __restrict__ g,
    _Float16* __restrict__ out, float extra_scale) {
  int row = blockIdx.x;  // 0..4095
  const _Float16* p = pre + (size_t)row * DIM;
  float vals[15];
  float ss = 0.f;
#pragma unroll
  for (int it = 0; it < 15; ++it) {
    float v = (float)p[threadIdx.x + it * 256];
    vals[it] = v;
    ss += v * v;
  }
#pragma unroll
  for (int off = 32; off > 0; off >>= 1) ss += __shfl_down(ss, off, 64);
  __shared__ float red[4];
  if ((threadIdx.x & 63) == 0) red[threadIdx.x >> 6] = ss;
  __syncthreads();
  float scale = rsqrtf((red[0] + red[1] + red[2] + red[3]) * (1.f / DIM) + 1e-6f) * extra_scale;
  int b = row >> 11, s = row & (SEQ - 1);
#pragma unroll
  for (int it = 0; it < 15; ++it) {
    int i = threadIdx.x + it * 256;
    int h = i >> 7, d = i & 127;
    out[(((size_t)b * NHEADS + h) * SEQ + s) * HDIM + d] = (_Float16)(vals[it] * g[i] * scale);
  }
}

// ---------------- Flash attention (mt=4, KVBLK=32, pipelined) -------------
// grid (S/128, B*H), 128 threads (2 waves), 64 q-rows per wave (mt=4).
// LDS 40KB bytes: [0,16384)      K dbuf: 2 x 32x128 (16-granule swz row&15)
//                 [16384,32768)  V dbuf: 2 x 128x32 (4-granule swz SWZ(row))
//                 [32768,40960)  P 128x32 (4-granule swz, wave-excl rows)
// Q (128x128, 32KB) staged through [0,32KB) before the loop.
// Per tile per wave: QK streams per-nt {4 kf reads, 16 MFMA, 16 exp+write},
// PV {4 pf + 8 vf reads, 32 MFMA}. 20 b128 + 32 b16 LDS ops serving 64 MFMA
// (2x the fragment reuse of the old mt=2 shape).
// Pipeline (R5-proven): prologue tiles 0,1; per iter vmcnt(8)+s_barrier;
// compute; s_barrier; stage tile t+2 into the vacated buffer.

__global__ __launch_bounds__(128, 2) void flash_attn_kernel(
    const _Float16* __restrict__ q, const _Float16* __restrict__ k,
    const _Float16* __restrict__ vT, _Float16* __restrict__ attnb) {
  __shared__ __align__(16) _Float16 smem[20480];  // 40 KB
  const int t = threadIdx.x, wave = t >> 6, lane = t & 63, quad = lane >> 4, l16 = lane & 15;
  const int qt = blockIdx.x, bh = blockIdx.y, b = bh / NHEADS, h = bh % NHEADS;
  const _Float16* qbase = q + ((size_t)bh * SEQ + qt * 128) * HDIM;
  const _Float16* kbase = k + (size_t)bh * SEQ * HDIM;
  const _Float16* vbase = vT + (size_t)bh * HDIM * SEQ;
  const int wq = wave * 64;

  // stage Q 128x128 (16-granule swizzle) through [0,32KB)
#pragma unroll
  for (int j = 0; j < 16; ++j) {
    int row = j * 8 + (t >> 4);
    int c = (t & 15) ^ (row & 15);
    __builtin_amdgcn_global_load_lds(GP(qbase + (size_t)row * HDIM + c * 8),
                                     LP(smem + j * 1024 + t * 8), 16, 0, 0);
  }
  __syncthreads();
  h8 qf[4][4];
#pragma unroll
  for (int mt = 0; mt < 4; ++mt)
#pragma unroll
    for (int ks = 0; ks < 4; ++ks) {
      int row = wq + mt * 16 + l16;   // row&15 == l16
      qf[mt][ks] = *reinterpret_cast<const h8*>(
          smem + row * 128 + (((ks * 4 + quad) ^ l16) * 8));
    }
  __syncthreads();

  f32x4 oacc[4][8] = {};
  float lst[4][4] = {};  // lane-partial softmax denominators (16 q-rows)

  // lane-invariant byte offsets
  int kOff[4];
#pragma unroll
  for (int ks = 0; ks < 4; ++ks)
    kOff[ks] = l16 * 256 + (((ks * 4 + quad) ^ l16) * 16);
  const int swzv = (l16 & 3) ^ ((l16 >> 2) & 3);
  const int vOff = 16384 + l16 * 64 + ((quad ^ swzv) << 4);
  const int pOff = 32768 + (wq + l16) * 64 + ((quad ^ swzv) << 4);
  int wOff[2];
  {
    int hi = l16 >> 3;
    int wb = 32768 + (wq + quad * 4) * 64 + (l16 & 7) * 2;
    wOff[0] = wb + ((hi ^ quad) << 4);
    wOff[1] = wb + (((2 + hi) ^ quad) << 4);
  }
  const char* smem_c = (const char*)smem;
  char* smem_w = (char*)smem;

  auto stageKV = [&](int tile, int bufi) {
    const int kt = tile * 32;
    _Float16* kb_ = smem + bufi * 4096;         // halfs (8KB buffers)
    _Float16* vb_ = smem + 8192 + bufi * 4096;  // VOFF = 16384 B = 8192 halfs
    // K tile: 32 keys x 128 d (16-granule swizzle row&15)
#pragma unroll
    for (int j = 0; j < 4; ++j) {
      int row = j * 8 + (t >> 4);
      int c = (t & 15) ^ (row & 15);
      __builtin_amdgcn_global_load_lds(GP(kbase + (size_t)(kt + row) * HDIM + c * 8),
                                       LP(kb_ + j * 1024 + t * 8), 16, 0, 0);
    }
    // V^T tile: 128 d x 32 s (4-granule swizzle SWZ(row))
#pragma unroll
    for (int j = 0; j < 4; ++j) {
      int row = j * 32 + (t >> 2);
      int c = (t & 3) ^ SWZ(row);
      __builtin_amdgcn_global_load_lds(GP(vbase + (size_t)row * SEQ + kt + c * 8),
                                       LP(vb_ + j * 1024 + t * 8), 16, 0, 0);
    }
  };

  // prologue: tiles 0,1 in flight (16 loads/thread)
  stageKV(0, 0);
  stageKV(1, 1);

  for (int tt = 0; tt < SEQ / 32; ++tt) {
    // own tile-tt loads landed (tile tt+1's 8 may remain), then barrier.
    asm volatile("s_waitcnt vmcnt(8)\n\ts_barrier" ::: "memory");

    const int kb = (tt & 1) << 13;  // 8192-byte K/V buffer toggle
    const char* kap = smem_c + kb;

    // S = Q K^T streamed per nt (16 k-cols); softmax immediately after.
#pragma unroll
    for (int nt = 0; nt < 2; ++nt) {
      f32x4 sacc[4] = {};
#pragma unroll
      for (int ks = 0; ks < 4; ++ks) {
        h8 kf = *reinterpret_cast<const h8*>(kap + kOff[ks] + nt * 4096);
#pragma unroll
        for (int mt = 0; mt < 4; ++mt)
          sacc[mt] = __builtin_amdgcn_mfma_f32_16x16x32_f16(qf[mt][ks], kf, sacc[mt], 0, 0, 0);
      }
      // p = exp(s-12): wave-exclusive P rows, lane-partial denominators
#pragma unroll
      for (int mt = 0; mt < 4; ++mt)
#pragma unroll
        for (int r = 0; r < 4; ++r) {
          float e = __expf(sacc[mt][r] - 12.0f);
          lst[mt][r] += e;
          *reinterpret_cast<_Float16*>(
              smem_w + ((wOff[nt] + mt * 1024 + r * 64) ^ (r << 4))) = (_Float16)e;
        }
    }

    // O += P V  (P rows wave-exclusive; intra-wave lgkmcnt orders it)
    h8 pf[4];
#pragma unroll
    for (int mt = 0; mt < 4; ++mt)
      pf[mt] = *reinterpret_cast<const h8*>(smem_c + pOff + mt * 1024);
    const char* vap = smem_c + kb;
#pragma unroll
    for (int nt = 0; nt < 8; ++nt) {
      h8 vf = *reinterpret_cast<const h8*>(vap + vOff + nt * 1024);
#pragma unroll
      for (int mt = 0; mt < 4; ++mt)
        oacc[mt][nt] = __builtin_amdgcn_mfma_f32_16x16x32_f16(pf[mt], vf, oacc[mt][nt], 0, 0, 0);
    }

    // all waves done reading K/V[tt&1] -> stage tile tt+2 there.
    asm volatile("s_barrier" ::: "memory");
    int dt = tt + 2;
    if (dt >= SEQ / 32) dt = SEQ / 32 - 1;  // clamp keeps vmcnt uniform
    stageKV(dt, tt & 1);
  }
  asm volatile("s_waitcnt vmcnt(0)" ::: "memory");  // drain tail stages

  // epilogue: reduce lane-partial denominators across l16, normalize, write
#pragma unroll
  for (int mt = 0; mt < 4; ++mt)
#pragma unroll
    for (int r = 0; r < 4; ++r) {
      float s = lst[mt][r];
#pragma unroll
      for (int off = 1; off <= 8; off <<= 1) s += __shfl_xor(s, off, 64);
      float inv = 1.f / s;
      int srow = qt * 128 + wq + mt * 16 + quad * 4 + r;
#pragma unroll
      for (int nt = 0; nt < 8; ++nt) {
        int d = nt * 16 + l16;
        attnb[((size_t)(b * SEQ + srow)) * DIM + h * HDIM + d] = (_Float16)(oacc[mt][nt][r] * inv);
      }
    }
}

// ---------------- launch ----------------

extern "C" void kernel_launch(void* const* d_in, const int* in_sizes, int n_in,
                              void* d_out, int out_size, void* d_ws, size_t ws_size,
                              hipStream_t stream) {
  const float* x  = (const float*)d_in[0];
  const float* Wq = (const float*)d_in[1];
  const float* bq = (const float*)d_in[2];
  const float* Wk = (const float*)d_in[3];
  const float* bk = (const float*)d_in[4];
  const float* Wv = (const float*)d_in[5];
  const float* bv = (const float*)d_in[6];
  const float* Wo = (const float*)d_in[7];
  const float* bo = (const float*)d_in[8];
  const float* gq = (const float*)d_in[9];
  const float* gk = (const float*)d_in[10];
  float* out = (float*)d_out;

  // workspace layout (total 186,777,600 B = 178.1 MiB)
  char* ws = (char*)d_ws;
  _Float16* xb    = (_Float16*)(ws);                 //  31,457,280 B
  _Float16* WT    = (_Float16*)(ws +  31457280LL);   //  29,491,200 B (reused x4)
  _Float16* qb    = (_Float16*)(ws +  60948480LL);   //  31,457,280 B
  _Float16* kb    = (_Float16*)(ws +  92405760LL);   //  31,457,280 B
  _Float16* vT    = (_Float16*)(ws + 123863040LL);   //  31,457,280 B
  _Float16* pre16 = (_Float16*)(ws + 155320320LL);   //  31,457,280 B
  _Float16* attnb = pre16;  // pre16 dead before flash writes attnb

  convert_h_kernel<<<15360, 256, 0, stream>>>(x, xb, MROWS * DIM);
  dim3 tgrid(DIM / 32, DIM / 32);
  const int ggrid = (DIM / 256) * (MROWS / 256);  // 15 * 16 = 240 blocks

  // Q
  transpose_convert_kernel<<<tgrid, 256, 0, stream>>>(Wq, WT, DIM, DIM);
  gemm_bt_kernel<_Float16><<<ggrid, 512, 0, stream>>>(xb, WT, bq, pre16, MROWS, DIM, DIM);
  rmsnorm_qk_kernel<<<MROWS, 256, 0, stream>>>(pre16, gq, qb, 0.08838834764831845f);  // 1/sqrt(128)
  // K
  transpose_convert_kernel<<<tgrid, 256, 0, stream>>>(Wk, WT, DIM, DIM);
  gemm_bt_kernel<_Float16><<<ggrid, 512, 0, stream>>>(xb, WT, bk, pre16, MROWS, DIM, DIM);
  rmsnorm_qk_kernel<<<MROWS, 256, 0, stream>>>(pre16, gk, kb, 1.0f);
  // V
  transpose_convert_kernel<<<tgrid, 256, 0, stream>>>(Wv, WT, DIM, DIM);
  gemm_bt_kernel<_Float16><<<ggrid, 512, 0, stream>>>(xb, WT, bv, pre16, MROWS, DIM, DIM);
  dim3 vgrid(SEQ / 32, HDIM / 32, BATCH * NHEADS);
  transpose_v_kernel<<<vgrid, 256, 0, stream>>>(pre16, vT);

  // attention
  dim3 agrid(SEQ / 128, BATCH * NHEADS);  // (16, 60)
  flash_attn_kernel<<<agrid, 128, 0, stream>>>(qb, kb, vT, attnb);

  // output projection
  transpose_convert_kernel<<<tgrid, 256, 0, stream>>>(Wo, WT, DIM, DIM);
  gemm_bt_kernel<float><<<ggrid, 512, 0, stream>>>(attnb, WT, bo, out, MROWS, DIM, DIM);
}

// Round 7
// 980.779 us; speedup vs baseline: 1.0405x; 1.0405x over previous
//
#include <hip/hip_runtime.h>

// ConnectorAttention on MI355X (gfx950), fp16-MFMA implementation.
// Round 10: flash mt=4 retry with conflict-free geometry: QBLK=256 (4 waves
//   x 64 q-rows), KVBLK=64 keeps the PROVEN 128B/256B-row swizzles (R9's
//   64B rows caused 13.8M bank conflicts). LDS 96KB (K dbuf 32K + V dbuf
//   32K + P 32K) -> 1 block/CU, 1 wave/SIMD; the counted-vmcnt pipeline
//   hides staging under a full tile of compute. Per 256 q-rows x 64 keys
//   LDS read issue drops 288 -> 160 b128 vs R7. GEMM reverted to R7-exact
//   (R8 addr-precompute was neutral-negative).
// Round 7: GEMM m201-style 4 phases/K-tile, BK=64, 2-deep dbuf, 128 KiB.
// Round 3-5: static-max softmax, counted-vmcnt pipelines, XOR swizzles.
// Round 2: workspace 178.1 MiB (reused WT buffer, fp16 pre, attnb aliases pre).

#define DIM 3840
#define NHEADS 30
#define HDIM 128
#define SEQ 2048
#define BATCH 2
#define MROWS (BATCH * SEQ)   // 4096

typedef _Float16 h8 __attribute__((ext_vector_type(8)));
typedef _Float16 h4 __attribute__((ext_vector_type(4)));
typedef float f32x4 __attribute__((ext_vector_type(4)));

#define GP(p) ((const __attribute__((address_space(1))) void*)(p))
#define LP(p) ((__attribute__((address_space(3))) void*)(p))

// ---------------- conversion kernels ----------------

__global__ __launch_bounds__(256) void convert_h_kernel(
    const float* __restrict__ in, _Float16* __restrict__ out, int n) {
  int i = (blockIdx.x * 256 + threadIdx.x) * 4;
  if (i + 3 < n) {
    float4 v = *reinterpret_cast<const float4*>(in + i);
    h4 o = {(_Float16)v.x, (_Float16)v.y, (_Float16)v.z, (_Float16)v.w};
    *reinterpret_cast<h4*>(out + i) = o;
  }
}

// W [rows][cols] fp32 -> Wt [cols][rows] fp16
__global__ __launch_bounds__(256) void transpose_convert_kernel(
    const float* __restrict__ W, _Float16* __restrict__ Wt, int rows, int cols) {
  __shared__ float tile[32][33];
  int c0 = blockIdx.x * 32, r0 = blockIdx.y * 32;
  int tc = threadIdx.x & 31, tr = threadIdx.x >> 5;
#pragma unroll
  for (int i = 0; i < 32; i += 8)
    tile[tr + i][tc] = W[(size_t)(r0 + tr + i) * cols + c0 + tc];
  __syncthreads();
#pragma unroll
  for (int i = 0; i < 32; i += 8)
    Wt[(size_t)(c0 + tr + i) * rows + r0 + tc] = (_Float16)tile[tc][tr + i];
}

// pre fp16 [B,S,H,D] -> vT fp16 [B,H,D,S]
__global__ __launch_bounds__(256) void transpose_v_kernel(
    const _Float16* __restrict__ pre, _Float16* __restrict__ vT) {
  __shared__ _Float16 tile[32][33];
  int s0 = blockIdx.x * 32, d0 = blockIdx.y * 32, bh = blockIdx.z;
  int b = bh / NHEADS, h = bh % NHEADS;
  int tc = threadIdx.x & 31, tr = threadIdx.x >> 5;
#pragma unroll
  for (int i = 0; i < 32; i += 8) {
    int s = s0 + tr + i, d = d0 + tc;
    tile[tr + i][tc] = pre[((size_t)(b * SEQ + s)) * DIM + h * HDIM + d];
  }
  __syncthreads();
#pragma unroll
  for (int i = 0; i < 32; i += 8) {
    int d = d0 + tr + i, s = s0 + tc;
    vT[((size_t)bh * HDIM + d) * SEQ + s] = tile[tc][tr + i];
  }
}

// ---------------- GEMM: C[M,N] = A[M,K] * Bt[N,K]^T + bias ----------------
// R7-exact. 256x256 tile, BK=64, 512 threads (8 waves, 2Mx4N), fp16 MFMA
// 16x16x32. LDS 128KB: 2 dbufs x (A 256x64 + B 256x64). 4 phases per
// K-tile; B(t+2) stages into the compute buffer at phase 4; one fused
// `s_waitcnt vmcnt(4); s_barrier` per K-tile.

template <typename OutT>
__global__ __launch_bounds__(512, 2) void gemm_bt_kernel(
    const _Float16* __restrict__ A, const _Float16* __restrict__ Bt,
    const float* __restrict__ bias, OutT* __restrict__ C,
    int M, int N, int K) {
  __shared__ __align__(16) _Float16 smem[65536];  // 2 x (A 16384 + B 16384)
  const int t = threadIdx.x;
  const int wave = t >> 6, lane = t & 63, quad = lane >> 4, l16 = lane & 15;

  // XCD-aware swizzle: nwg=240, 240%8==0 -> bijective simple form
  const int nwg = gridDim.x;
  const int cpx = nwg >> 3;
  const int bid = blockIdx.x;
  const int swz = (bid & 7) * cpx + (bid >> 3);
  const int ntx = N >> 8;                     // tiles along N (15)
  const int bm = (swz / ntx) << 8, bn = (swz % ntx) << 8;
  const int wm = (wave >> 2) * 128, wn = (wave & 3) * 64;

  const _Float16* Abase = A + (size_t)bm * K;
  const _Float16* Bbase = Bt + (size_t)bn * K;
  const int NT = K >> 6;                      // K-tiles of 64 (60)

  f32x4 acc[8][4] = {};

  // stage one half (128 rows x 64 halfs = 16KB) of A (isB=0) or B (isB=1)
  auto stage_half = [&](const _Float16* Gb, int d, int isB, int h, int k0) {
    _Float16* Lb = smem + d * 32768 + isB * 16384 + h * 8192;
#pragma unroll
    for (int L = 0; L < 2; ++L) {
      int slot = L * 512 + t;                 // 0..1023
      int row = h * 128 + (slot >> 3);        // tile row 0..255
      int gs = (slot & 7) ^ (row & 7);        // pre-swizzled source granule
      __builtin_amdgcn_global_load_lds(GP(Gb + (size_t)row * K + k0 + gs * 8),
                                       LP(Lb + slot * 8), 16, 0, 0);
    }
  };

  // prologue: B(0), A(0), B(1) -- 12 loads/thread; wait A(0)+B(0) (8 pops).
  stage_half(Bbase, 0, 1, 0, 0);  stage_half(Bbase, 0, 1, 1, 0);
  stage_half(Abase, 0, 0, 0, 0);  stage_half(Abase, 0, 0, 1, 0);
  stage_half(Bbase, 1, 1, 0, 64); stage_half(Bbase, 1, 1, 1, 64);
  asm volatile("s_waitcnt vmcnt(4)\n\ts_barrier" ::: "memory");

  for (int tt = 0; tt < NT; ++tt) {
    const _Float16* bufA = smem + (tt & 1) * 32768;
    const _Float16* bufB = bufA + 16384;
    const int dnx = (tt + 1) & 1;
    const int k1 = (tt + 1 < NT ? tt + 1 : NT - 1) << 6;  // A(t+1), clamped
    const int k2 = (tt + 2 < NT ? tt + 2 : NT - 1) << 6;  // B(t+2), clamped
    h8 afl[4], afh[4], bf[4];

    // ---- phase 1: read bf[ks0], afl[ks0]; stage A_lo(t+1); Qlo x ks0 ----
#pragma unroll
    for (int ni = 0; ni < 4; ++ni) {
      int row = wn + ni * 16 + l16;
      bf[ni] = *reinterpret_cast<const h8*>(bufB + row * 64 + ((quad ^ (row & 7)) * 8));
    }
#pragma unroll
    for (int mi = 0; mi < 4; ++mi) {
      int row = wm + mi * 16 + l16;
      afl[mi] = *reinterpret_cast<const h8*>(bufA + row * 64 + ((quad ^ (row & 7)) * 8));
    }
    stage_half(Abase, dnx, 0, 0, k1);
    __builtin_amdgcn_s_barrier();
    asm volatile("s_waitcnt lgkmcnt(0)" ::: "memory");
    __builtin_amdgcn_sched_barrier(0);
    __builtin_amdgcn_s_setprio(1);
#pragma unroll
    for (int mi = 0; mi < 4; ++mi)
#pragma unroll
      for (int ni = 0; ni < 4; ++ni)
        acc[mi][ni] = __builtin_amdgcn_mfma_f32_16x16x32_f16(afl[mi], bf[ni], acc[mi][ni], 0, 0, 0);
    __builtin_amdgcn_s_setprio(0);
    __builtin_amdgcn_s_barrier();

    // ---- phase 2: read afh[ks0]; stage A_hi(t+1); Qhi x ks0 ----
#pragma unroll
    for (int mi = 0; mi < 4; ++mi) {
      int row = wm + 64 + mi * 16 + l16;
      afh[mi] = *reinterpret_cast<const h8*>(bufA + row * 64 + ((quad ^ (row & 7)) * 8));
    }
    stage_half(Abase, dnx, 0, 1, k1);
    __builtin_amdgcn_s_barrier();
    asm volatile("s_waitcnt lgkmcnt(0)" ::: "memory");
    __builtin_amdgcn_sched_barrier(0);
    __builtin_amdgcn_s_setprio(1);
#pragma unroll
    for (int mi = 0; mi < 4; ++mi)
#pragma unroll
      for (int ni = 0; ni < 4; ++ni)
        acc[4 + mi][ni] = __builtin_amdgcn_mfma_f32_16x16x32_f16(afh[mi], bf[ni], acc[4 + mi][ni], 0, 0, 0);
    __builtin_amdgcn_s_setprio(0);
    __builtin_amdgcn_s_barrier();

    // ---- phase 3: read bf[ks1], afl[ks1]; no stage; Qlo x ks1 ----
#pragma unroll
    for (int ni = 0; ni < 4; ++ni) {
      int row = wn + ni * 16 + l16;
      bf[ni] = *reinterpret_cast<const h8*>(bufB + row * 64 + (((4 + quad) ^ (row & 7)) * 8));
    }
#pragma unroll
    for (int mi = 0; mi < 4; ++mi) {
      int row = wm + mi * 16 + l16;
      afl[mi] = *reinterpret_cast<const h8*>(bufA + row * 64 + (((4 + quad) ^ (row & 7)) * 8));
    }
    __builtin_amdgcn_s_barrier();
    asm volatile("s_waitcnt lgkmcnt(0)" ::: "memory");
    __builtin_amdgcn_sched_barrier(0);
    __builtin_amdgcn_s_setprio(1);
#pragma unroll
    for (int mi = 0; mi < 4; ++mi)
#pragma unroll
      for (int ni = 0; ni < 4; ++ni)
        acc[mi][ni] = __builtin_amdgcn_mfma_f32_16x16x32_f16(afl[mi], bf[ni], acc[mi][ni], 0, 0, 0);
    __builtin_amdgcn_s_setprio(0);
    __builtin_amdgcn_s_barrier();

    // ---- phase 4: read afh[ks1]; stage B(t+2) into THIS buf (B dead);
    //      Qhi x ks1; fused vmcnt(4)+barrier = K-tile boundary ----
#pragma unroll
    for (int mi = 0; mi < 4; ++mi) {
      int row = wm + 64 + mi * 16 + l16;
      afh[mi] = *reinterpret_cast<const h8*>(bufA + row * 64 + (((4 + quad) ^ (row & 7)) * 8));
    }
    stage_half(Bbase, tt & 1, 1, 0, k2);
    stage_half(Bbase, tt & 1, 1, 1, k2);
    __builtin_amdgcn_s_barrier();
    asm volatile("s_waitcnt lgkmcnt(0)" ::: "memory");
    __builtin_amdgcn_sched_barrier(0);
    __builtin_amdgcn_s_setprio(1);
#pragma unroll
    for (int mi = 0; mi < 4; ++mi)
#pragma unroll
      for (int ni = 0; ni < 4; ++ni)
        acc[4 + mi][ni] = __builtin_amdgcn_mfma_f32_16x16x32_f16(afh[mi], bf[ni], acc[4 + mi][ni], 0, 0, 0);
    __builtin_amdgcn_s_setprio(0);
    asm volatile("s_waitcnt vmcnt(4)\n\ts_barrier" ::: "memory");
  }

  // drain the tail stages before LDS goes away with the wave
  asm volatile("s_waitcnt vmcnt(0)" ::: "memory");

#pragma unroll
  for (int ni = 0; ni < 4; ++ni) {
    int col = bn + wn + ni * 16 + l16;
    float bv = bias[col];
#pragma unroll
    for (int mi = 0; mi < 8; ++mi) {
      int row0 = bm + wm + mi * 16 + quad * 4;
#pragma unroll
      for (int r = 0; r < 4; ++r)
        C[(size_t)(row0 + r) * N + col] = (OutT)(acc[mi][ni][r] + bv);
    }
  }
}

// ---------------- RMSNorm (row of 3840, fp16 in) -> fp16 [B,H,S,D] --------

__global__ __launch_bounds__(256) void rmsnorm_qk_kernel(
    const _Float16* __restrict__ pre, const float* __restrict__ g,
    _Float16* __restrict__ out, float extra_scale) {
  int row = blockIdx.x;  // 0..4095
  const _Float16* p = pre + (size_t)row * DIM;
  float vals[15];
  float ss = 0.f;
#pragma unroll
  for (int it = 0; it < 15; ++it) {
    float v = (float)p[threadIdx.x + it * 256];
    vals[it] = v;
    ss += v * v;
  }
#pragma unroll
  for (int off = 32; off > 0; off >>= 1) ss += __shfl_down(ss, off, 64);
  __shared__ float red[4];
  if ((threadIdx.x & 63) == 0) red[threadIdx.x >> 6] = ss;
  __syncthreads();
  float scale = rsqrtf((red[0] + red[1] + red[2] + red[3]) * (1.f / DIM) + 1e-6f) * extra_scale;
  int b = row >> 11, s = row & (SEQ - 1);
#pragma unroll
  for (int it = 0; it < 15; ++it) {
    int i = threadIdx.x + it * 256;
    int h = i >> 7, d = i & 127;
    out[(((size_t)b * NHEADS + h) * SEQ + s) * HDIM + d] = (_Float16)(vals[it] * g[i] * scale);
  }
}

// ---------------- Flash attention (mt=4, QBLK=256, KVBLK=64) --------------
// grid (S/256, B*H), 256 threads (4 waves), 64 q-rows per wave (mt=4).
// LDS 96KB bytes: [0,32768)      K dbuf: 2 x 64x128 (16-granule swz row&15)
//                 [32768,65536)  V dbuf: 2 x 128x64 (8-granule swz row&7)
//                 [65536,98304)  P 256x64 (8-granule swz, wave-excl rows)
// Q (256x128, 64KB) staged through [0,64KB) before the loop.
// All row geometries identical to the R7-proven zero-conflict layouts.
// Per wave per 64-key tile: QK {16 kf b128, 64 MFMA}, softmax {64 exp +
// 64 b16 writes}, PV {8 pf + 16 vf b128, 64 MFMA} -- 40 b128 / 128 MFMA,
// half the read issue per MFMA of the R7 shape.
// Pipeline (R5/R7-proven): prologue tiles 0,1; per iter vmcnt(8)+s_barrier;
// compute; s_barrier; stage tile t+2 into the vacated buffer. 1 block/CU
// (LDS-capped) -- the deep pipeline carries the latency hiding.

__global__ __launch_bounds__(256) void flash_attn_kernel(
    const _Float16* __restrict__ q, const _Float16* __restrict__ k,
    const _Float16* __restrict__ vT, _Float16* __restrict__ attnb) {
  __shared__ __align__(16) _Float16 smem[49152];  // 96 KB
  const int t = threadIdx.x, wave = t >> 6, lane = t & 63, quad = lane >> 4, l16 = lane & 15;
  const int qt = blockIdx.x, bh = blockIdx.y, b = bh / NHEADS, h = bh % NHEADS;
  const _Float16* qbase = q + ((size_t)bh * SEQ + qt * 256) * HDIM;
  const _Float16* kbase = k + (size_t)bh * SEQ * HDIM;
  const _Float16* vbase = vT + (size_t)bh * HDIM * SEQ;
  const int wq = wave * 64;

  // stage Q 256x128 (16-granule swizzle) through [0,64KB)
#pragma unroll
  for (int j = 0; j < 16; ++j) {
    int row = j * 16 + (t >> 4);
    int c = (t & 15) ^ (row & 15);
    __builtin_amdgcn_global_load_lds(GP(qbase + (size_t)row * HDIM + c * 8),
                                     LP(smem + j * 2048 + t * 8), 16, 0, 0);
  }
  __syncthreads();  // full drain: Q visible
  h8 qf[4][4];
#pragma unroll
  for (int mt = 0; mt < 4; ++mt)
#pragma unroll
    for (int ks = 0; ks < 4; ++ks) {
      int row = wq + mt * 16 + l16;   // row&15 == l16
      qf[mt][ks] = *reinterpret_cast<const h8*>(
          smem + row * 128 + (((ks * 4 + quad) ^ l16) * 8));
    }
  __syncthreads();  // all waves own Q frags before K/V staging overwrites

  f32x4 oacc[4][8] = {};
  float lst[4][4] = {};  // lane-partial softmax denominators

  auto stageKV = [&](int tile, int bufi) {
    const int kt = tile * 64;
    _Float16* kb_ = smem + bufi * 8192;          // K: 16KB buffers
    _Float16* vb_ = smem + 16384 + bufi * 8192;  // V: base 32768 B
    // K tile: 64 keys x 128 d (16-granule swizzle row&15)
#pragma unroll
    for (int j = 0; j < 4; ++j) {
      int row = j * 16 + (t >> 4);
      int c = (t & 15) ^ (row & 15);
      __builtin_amdgcn_global_load_lds(GP(kbase + (size_t)(kt + row) * HDIM + c * 8),
                                       LP(kb_ + j * 2048 + t * 8), 16, 0, 0);
    }
    // V^T tile: 128 d x 64 s (8-granule swizzle row&7)
#pragma unroll
    for (int j = 0; j < 4; ++j) {
      int row = j * 32 + (t >> 3);
      int c = (t & 7) ^ (row & 7);
      __builtin_amdgcn_global_load_lds(GP(vbase + (size_t)row * SEQ + kt + c * 8),
                                       LP(vb_ + j * 2048 + t * 8), 16, 0, 0);
    }
  };

  // prologue: tiles 0,1 in flight (16 loads/thread)
  stageKV(0, 0);
  stageKV(1, 1);

  // lane-invariant byte offsets (all rows' &7/&15 terms reduce to l16)
  int kOff[4], vOff[2], pOff[2];
#pragma unroll
  for (int ks = 0; ks < 4; ++ks)
    kOff[ks] = l16 * 256 + (((ks * 4 + quad) ^ l16) * 16);
#pragma unroll
  for (int ks = 0; ks < 2; ++ks) {
    vOff[ks] = 32768 + l16 * 128 + (((ks * 4 + quad) ^ (l16 & 7)) * 16);
    pOff[ks] = 65536 + (wq + l16) * 128 + (((ks * 4 + quad) ^ (l16 & 7)) * 16);
  }
  const char* smem_c = (const char*)smem;
  char* smem_w = (char*)smem;

  for (int tt = 0; tt < SEQ / 64; ++tt) {
    // own tile-tt loads landed (tile tt+1's 8 may remain), then barrier.
    asm volatile("s_waitcnt vmcnt(8)\n\ts_barrier" ::: "memory");

    const int kb = (tt & 1) << 14;  // 16384-byte K/V buffer toggle

    // S = Q K^T streamed per nt (16 k-cols); softmax immediately after.
#pragma unroll
    for (int nt = 0; nt < 4; ++nt) {
      f32x4 sacc[4] = {};
#pragma unroll
      for (int ks = 0; ks < 4; ++ks) {
        h8 kf = *reinterpret_cast<const h8*>(smem_c + (kOff[ks] + kb) + nt * 4096);
#pragma unroll
        for (int mt = 0; mt < 4; ++mt)
          sacc[mt] = __builtin_amdgcn_mfma_f32_16x16x32_f16(qf[mt][ks], kf, sacc[mt], 0, 0, 0);
      }
      // p = exp(s-12): wave-exclusive P rows, lane-partial denominators
      int colg = nt * 2 + (l16 >> 3);
      int ce = l16 & 7;
#pragma unroll
      for (int mt = 0; mt < 4; ++mt)
#pragma unroll
        for (int r = 0; r < 4; ++r) {
          float e = __expf(sacc[mt][r] - 12.0f);
          lst[mt][r] += e;
          int rowl = quad * 4 + r;
          smem[32768 + (wq + mt * 16 + rowl) * 64 + ((colg ^ (rowl & 7)) * 8) + ce] = (_Float16)e;
        }
    }

    // O += P V  (P rows wave-exclusive; intra-wave lgkmcnt orders it)
#pragma unroll
    for (int ks = 0; ks < 2; ++ks) {
      h8 pf[4];
#pragma unroll
      for (int mt = 0; mt < 4; ++mt)
        pf[mt] = *reinterpret_cast<const h8*>(smem_c + pOff[ks] + mt * 2048);
#pragma unroll
      for (int nt = 0; nt < 8; ++nt) {
        h8 vf = *reinterpret_cast<const h8*>(smem_c + (vOff[ks] + kb) + nt * 2048);
#pragma unroll
        for (int mt = 0; mt < 4; ++mt)
          oacc[mt][nt] = __builtin_amdgcn_mfma_f32_16x16x32_f16(pf[mt], vf, oacc[mt][nt], 0, 0, 0);
      }
    }

    // all waves done reading K/V[tt&1] -> stage tile tt+2 there.
    asm volatile("s_barrier" ::: "memory");
    int dt = tt + 2;
    if (dt >= SEQ / 64) dt = SEQ / 64 - 1;  // clamp keeps vmcnt uniform
    stageKV(dt, tt & 1);
  }
  asm volatile("s_waitcnt vmcnt(0)" ::: "memory");  // drain tail stages

  // epilogue: reduce lane-partial denominators across l16, normalize, write
#pragma unroll
  for (int mt = 0; mt < 4; ++mt)
#pragma unroll
    for (int r = 0; r < 4; ++r) {
      float s = lst[mt][r];
#pragma unroll
      for (int off = 1; off <= 8; off <<= 1) s += __shfl_xor(s, off, 64);
      float inv = 1.f / s;
      int srow = qt * 256 + wq + mt * 16 + quad * 4 + r;
#pragma unroll
      for (int nt = 0; nt < 8; ++nt) {
        int d = nt * 16 + l16;
        attnb[((size_t)(b * SEQ + srow)) * DIM + h * HDIM + d] = (_Float16)(oacc[mt][nt][r] * inv);
      }
    }
}

// ---------------- launch ----------------

extern "C" void kernel_launch(void* const* d_in, const int* in_sizes, int n_in,
                              void* d_out, int out_size, void* d_ws, size_t ws_size,
                              hipStream_t stream) {
  const float* x  = (const float*)d_in[0];
  const float* Wq = (const float*)d_in[1];
  const float* bq = (const float*)d_in[2];
  const float* Wk = (const float*)d_in[3];
  const float* bk = (const float*)d_in[4];
  const float* Wv = (const float*)d_in[5];
  const float* bv = (const float*)d_in[6];
  const float* Wo = (const float*)d_in[7];
  const float* bo = (const float*)d_in[8];
  const float* gq = (const float*)d_in[9];
  const float* gk = (const float*)d_in[10];
  float* out = (float*)d_out;

  // workspace layout (total 186,777,600 B = 178.1 MiB)
  char* ws = (char*)d_ws;
  _Float16* xb    = (_Float16*)(ws);                 //  31,457,280 B
  _Float16* WT    = (_Float16*)(ws +  31457280LL);   //  29,491,200 B (reused x4)
  _Float16* qb    = (_Float16*)(ws +  60948480LL);   //  31,457,280 B
  _Float16* kb    = (_Float16*)(ws +  92405760LL);   //  31,457,280 B
  _Float16* vT    = (_Float16*)(ws + 123863040LL);   //  31,457,280 B
  _Float16* pre16 = (_Float16*)(ws + 155320320LL);   //  31,457,280 B
  _Float16* attnb = pre16;  // pre16 dead before flash writes attnb

  convert_h_kernel<<<15360, 256, 0, stream>>>(x, xb, MROWS * DIM);
  dim3 tgrid(DIM / 32, DIM / 32);
  const int ggrid = (DIM / 256) * (MROWS / 256);  // 15 * 16 = 240 blocks

  // Q
  transpose_convert_kernel<<<tgrid, 256, 0, stream>>>(Wq, WT, DIM, DIM);
  gemm_bt_kernel<_Float16><<<ggrid, 512, 0, stream>>>(xb, WT, bq, pre16, MROWS, DIM, DIM);
  rmsnorm_qk_kernel<<<MROWS, 256, 0, stream>>>(pre16, gq, qb, 0.08838834764831845f);  // 1/sqrt(128)
  // K
  transpose_convert_kernel<<<tgrid, 256, 0, stream>>>(Wk, WT, DIM, DIM);
  gemm_bt_kernel<_Float16><<<ggrid, 512, 0, stream>>>(xb, WT, bk, pre16, MROWS, DIM, DIM);
  rmsnorm_qk_kernel<<<MROWS, 256, 0, stream>>>(pre16, gk, kb, 1.0f);
  // V
  transpose_convert_kernel<<<tgrid, 256, 0, stream>>>(Wv, WT, DIM, DIM);
  gemm_bt_kernel<_Float16><<<ggrid, 512, 0, stream>>>(xb, WT, bv, pre16, MROWS, DIM, DIM);
  dim3 vgrid(SEQ / 32, HDIM / 32, BATCH * NHEADS);
  transpose_v_kernel<<<vgrid, 256, 0, stream>>>(pre16, vT);

  // attention
  dim3 agrid(SEQ / 256, BATCH * NHEADS);  // (8, 60)
  flash_attn_kernel<<<agrid, 256, 0, stream>>>(qb, kb, vT, attnb);

  // output projection
  transpose_convert_kernel<<<tgrid, 256, 0, stream>>>(Wo, WT, DIM, DIM);
  gemm_bt_kernel<float><<<ggrid, 512, 0, stream>>>(attnb, WT, bo, out, MROWS, DIM, DIM);
}